// Round 3
// baseline (206.706 us; speedup 1.0000x reference)
//
#include <hip/hip_runtime.h>

#define NTH 512   // 8 waves; 32 rows/block (2x16-row tiles); grid 256 -> 1 block/CU

typedef _Float16 half8 __attribute__((ext_vector_type(8)));
typedef __attribute__((ext_vector_type(4))) float floatx4;

#define LOG2E 1.44269504088896340736f

// DPP add stage; 0x140,0x141,0x4E,0xB1 together = 16-lane sum broadcast
template<int CTRL>
__device__ __forceinline__ float dpp_add(float v) {
    int o = __builtin_amdgcn_update_dpp(0, __float_as_int(v), CTRL, 0xF, 0xF, true);
    return v + __int_as_float(o);
}

#define MFMA16 __builtin_amdgcn_mfma_f32_16x16x32_f16

// ---------------------------------------------------------------------------
// Encoder layer: [32,128] (LDS) @ W[128,128] + bias -> [32,128] (LDS)
// 512 threads: c = tid&127 (out col), g = tid>>7 (row group of 8)
// ---------------------------------------------------------------------------
template<bool RELU>
__device__ __forceinline__ void mlp_layer(const float (*in)[132],
                                          const float* __restrict__ W,
                                          const float* __restrict__ bias,
                                          float (*outl)[132], int c, int g) {
    float acc[8];
    #pragma unroll
    for (int i = 0; i < 8; i++) acc[i] = 0.f;
    for (int k = 0; k < 128; k += 4) {
        float w0 = W[(k + 0) * 128 + c];
        float w1 = W[(k + 1) * 128 + c];
        float w2 = W[(k + 2) * 128 + c];
        float w3 = W[(k + 3) * 128 + c];
        #pragma unroll
        for (int i = 0; i < 8; i++) {
            const float4 xv = *(const float4*)&in[g * 8 + i][k];
            acc[i] = fmaf(xv.x, w0, fmaf(xv.y, w1, fmaf(xv.z, w2, fmaf(xv.w, w3, acc[i]))));
        }
    }
    const float bv = bias[c];
    #pragma unroll
    for (int i = 0; i < 8; i++) {
        float v = acc[i] + bv;
        outl[g * 8 + i][c] = RELU ? fmaxf(v, 0.f) : v;
    }
}

// ---------------------------------------------------------------------------
// Fused encoder + 50-iter GRU + decoder. TWO independent 16-row batch tiles
// per block, interleaved inside each wave: every serial chain (MFMA
// accumulate, DPP reduce, trans chain, LDS round trip) has a twin
// independent chain for ILP. Weights are shared across tiles (no extra
// register cost). Grid 256 -> 1 block/CU -> 256-reg/wave budget: W_hh (48)
// AND decoder weights (16) both persist in registers; no LDS weight reads.
// h16 uses chunk-rotation swizzle (chunk+row)&15: 16B-aligned b128 reads
// spread evenly over bank groups (kills the stride-136 4-way conflicts).
// ---------------------------------------------------------------------------
__global__ __launch_bounds__(NTH, 2)
void gru_fused_kernel(const float* __restrict__ x,
                      const float* __restrict__ ew0, const float* __restrict__ eb0,
                      const float* __restrict__ ew1, const float* __restrict__ eb1,
                      const float* __restrict__ ew2, const float* __restrict__ eb2,
                      const float* __restrict__ w_ih, const float* __restrict__ w_hh,
                      const float* __restrict__ b_ih, const float* __restrict__ b_hh,
                      const float* __restrict__ dw0, const float* __restrict__ db0,
                      const float* __restrict__ dw1, const float* __restrict__ db1,
                      float* __restrict__ out) {
    __shared__ float hA[32][132];                          // encoder staging
    __shared__ float smemB[32 * 132];                      // encoder ping buffer
    // [dbuf][tile][row][chunk][elem]; swizzled chunk = (j/8 + row) & 15
    __shared__ __align__(16) _Float16 h16[2][2][16][16][8];
    __shared__ float outb[32][52];

    const int tid  = threadIdx.x;
    const int b0   = blockIdx.x * 32;
    const int lane = tid & 63;
    const int w    = tid >> 6;     // wave 0..7
    const int quad = lane >> 4;
    const int l15  = lane & 15;

    // ---------------- encoder: x -> hA (32 rows) ----------------
    {
        const int c = tid & 127;
        const int g = tid >> 7;    // 0..3, 8 rows each
        float acc[8];
        #pragma unroll
        for (int i = 0; i < 8; i++) acc[i] = 0.f;
        for (int k = 0; k < 256; k += 4) {
            float w0 = ew0[(k + 0) * 128 + c];
            float w1 = ew0[(k + 1) * 128 + c];
            float w2 = ew0[(k + 2) * 128 + c];
            float w3 = ew0[(k + 3) * 128 + c];
            #pragma unroll
            for (int i = 0; i < 8; i++) {
                const float4 xv = *(const float4*)(x + (size_t)(b0 + g * 8 + i) * 256 + k);
                acc[i] = fmaf(xv.x, w0, fmaf(xv.y, w1, fmaf(xv.z, w2, fmaf(xv.w, w3, acc[i]))));
            }
        }
        float bv = eb0[c];
        #pragma unroll
        for (int i = 0; i < 8; i++) hA[g * 8 + i][c] = fmaxf(acc[i] + bv, 0.f);
        __syncthreads();
        mlp_layer<true>(hA, ew1, eb1, (float(*)[132])smemB, c, g);
        __syncthreads();
        mlp_layer<false>((float(*)[132])smemB, ew2, eb2, hA, c, g);
        __syncthreads();
    }

    // ---------------- persistent register weights (f16, pre-scaled) --------
    // wave w owns gate col jc = g*128 + w*16 + l15, for BOTH row tiles
    const int jc = w * 16 + l15;
    half8 wb16[3][4];
    #pragma unroll
    for (int g = 0; g < 3; g++) {
        const float scale = (g == 2) ? 2.f * LOG2E : LOG2E;
        const float* wrow = w_hh + (g * 128 + jc) * 128;
        #pragma unroll
        for (int kt = 0; kt < 4; kt++) {
            const int kb = kt * 32 + quad * 8;
            half8 hv;
            #pragma unroll
            for (int e = 0; e < 8; e++) hv[e] = (_Float16)(wrow[kb + e] * scale);
            wb16[g][kt] = hv;
        }
    }
    half8 dw16[4];
    #pragma unroll
    for (int kt = 0; kt < 4; kt++) {
        half8 hv;
        #pragma unroll
        for (int e = 0; e < 8; e++)
            hv[e] = (_Float16)dw0[(kt * 32 + quad * 8 + e) * 16 + l15];
        dw16[kt] = hv;
    }
    // gate constants (pre-scaled; biases fold into acc init)
    const float wihc0 = w_ih[jc] * LOG2E;
    const float wihc1 = w_ih[128 + jc] * LOG2E;
    const float wihc2 = w_ih[256 + jc] * (2.f * LOG2E);
    const float bs0   = (b_ih[jc] + b_hh[jc]) * LOG2E;
    const float bs1   = (b_ih[128 + jc] + b_hh[128 + jc]) * LOG2E;
    const float bhhn  = b_hh[256 + jc] * (2.f * LOG2E);
    const float bihn  = b_ih[256 + jc] * (2.f * LOG2E);
    const float db0r = db0[l15];
    const float dw1r = dw1[l15];
    const float db1r = db1[0];

    // ---------------- init planes[0] (swizzled) + lane-private fp32 h ------
    for (int i = tid; i < 2 * 16 * 128; i += NTH) {
        const int u = i >> 11, b = (i >> 7) & 15, j = i & 127;
        h16[0][u][b][((j >> 3) + b) & 15][j & 7] = (_Float16)hA[u * 16 + b][j];
    }
    if (tid < 32) outb[tid][0] = 0.f;
    float hold[2][4];   // h at (tile u, row quad*4+reg, col jc)
    #pragma unroll
    for (int u = 0; u < 2; u++)
        #pragma unroll
        for (int reg = 0; reg < 4; reg++)
            hold[u][reg] = hA[u * 16 + quad * 4 + reg][jc];
    __syncthreads();

    const int rbase = quad + l15;          // read-swizzle lane constant
    const int wch   = jc >> 3;             // write-swizzle chunk base
    const int wjl   = jc & 7;

    // ---------------- 50 iterations ----------------
    for (int t = 0; t <= 49; t++) {
        const int cur = t & 1, nxt = cur ^ 1;
        const _Float16* __restrict__ hc = &h16[cur][0][0][0][0];
        _Float16* __restrict__ hn_ = &h16[nxt][0][0][0][0];

        // A-frags for both tiles (8x ds_read_b128, swizzled, conflict-free)
        half8 ah[2][4];
        #pragma unroll
        for (int u = 0; u < 2; u++)
            #pragma unroll
            for (int kt = 0; kt < 4; kt++)
                ah[u][kt] = *(const half8*)(hc + u * 2048 + l15 * 128 +
                                            (((kt * 4 + rbase) & 15) << 3));

        // decoder MFMAs first (dacc feeds the serial reduce->gate chain)
        floatx4 dacc[2];
        dacc[0] = (floatx4){0.f, 0.f, 0.f, 0.f};
        dacc[1] = (floatx4){0.f, 0.f, 0.f, 0.f};
        #pragma unroll
        for (int kt = 0; kt < 4; kt++) {
            dacc[0] = MFMA16(ah[0][kt], dw16[kt], dacc[0], 0, 0, 0);
            dacc[1] = MFMA16(ah[1][kt], dw16[kt], dacc[1], 0, 0, 0);
        }

        // GRU MFMAs: 6 independent 4-deep chains (3 gates x 2 tiles)
        floatx4 acc[3][2];
        #pragma unroll
        for (int u = 0; u < 2; u++) {
            acc[0][u] = (floatx4){bs0, bs0, bs0, bs0};
            acc[1][u] = (floatx4){bs1, bs1, bs1, bs1};
            acc[2][u] = (floatx4){bhhn, bhhn, bhhn, bhhn};
        }
        #pragma unroll
        for (int kt = 0; kt < 4; kt++)
            #pragma unroll
            for (int g = 0; g < 3; g++) {
                acc[g][0] = MFMA16(ah[0][kt], wb16[g][kt], acc[g][0], 0, 0, 0);
                acc[g][1] = MFMA16(ah[1][kt], wb16[g][kt], acc[g][1], 0, 0, 0);
            }

        // decoder reduce via DPP: 8 independent 4-stage chains
        float xp[2][4];
        #pragma unroll
        for (int u = 0; u < 2; u++)
            #pragma unroll
            for (int reg = 0; reg < 4; reg++) {
                float v = fmaxf(dacc[u][reg] + db0r, 0.f) * dw1r;
                v = dpp_add<0x140>(v);   // row_mirror
                v = dpp_add<0x141>(v);   // row_half_mirror
                v = dpp_add<0x4E>(v);    // quad_perm xor2
                v = dpp_add<0xB1>(v);    // quad_perm xor1
                xp[u][reg] = (t == 0) ? 0.f : (v + db1r);
            }
        if (t > 0 && w == 0 && l15 == 0) {
            #pragma unroll
            for (int u = 0; u < 2; u++)
                #pragma unroll
                for (int reg = 0; reg < 4; reg++)
                    outb[u * 16 + quad * 4 + reg][t] = xp[u][reg];
        }

        // gates -> h_{t+1}: 8 independent trans chains
        if (t < 49) {
            #pragma unroll
            for (int u = 0; u < 2; u++)
                #pragma unroll
                for (int reg = 0; reg < 4; reg++) {
                    const int b = quad * 4 + reg;
                    const float xpv = xp[u][reg];
                    float gr = fmaf(xpv, wihc0, acc[0][u][reg]);
                    float gz = fmaf(xpv, wihc1, acc[1][u][reg]);
                    float rg = __builtin_amdgcn_rcpf(1.f + __builtin_amdgcn_exp2f(-gr));
                    float zg = __builtin_amdgcn_rcpf(1.f + __builtin_amdgcn_exp2f(-gz));
                    float ys = fmaf(rg, acc[2][u][reg], fmaf(xpv, wihc2, bihn));
                    float ng = fmaf(-2.f, __builtin_amdgcn_rcpf(__builtin_amdgcn_exp2f(ys) + 1.f), 1.f);
                    const float hv = fmaf(zg, hold[u][reg] - ng, ng);
                    hold[u][reg] = hv;
                    hn_[u * 2048 + b * 128 + (((wch + b) & 15) << 3) + wjl] = (_Float16)hv;
                }
        }
        __syncthreads();   // planes[nxt] complete; outb[t] visible
    }

    // coalesced output write: [32 rows][50 cols], col 0 = 0
    for (int e = tid; e < 32 * 50; e += NTH) {
        out[(size_t)b0 * 50 + e] = outb[e / 50][e % 50];
    }
}

// ---------------------------------------------------------------------------
extern "C" void kernel_launch(void* const* d_in, const int* in_sizes, int n_in,
                              void* d_out, int out_size, void* d_ws, size_t ws_size,
                              hipStream_t stream) {
    const float* x   = (const float*)d_in[0];
    const float* ew0 = (const float*)d_in[1];
    const float* eb0 = (const float*)d_in[2];
    const float* ew1 = (const float*)d_in[3];
    const float* eb1 = (const float*)d_in[4];
    const float* ew2 = (const float*)d_in[5];
    const float* eb2 = (const float*)d_in[6];
    const float* wih = (const float*)d_in[7];
    const float* whh = (const float*)d_in[8];
    const float* bih = (const float*)d_in[9];
    const float* bhh = (const float*)d_in[10];
    const float* dw0 = (const float*)d_in[11];
    const float* db0 = (const float*)d_in[12];
    const float* dw1 = (const float*)d_in[13];
    const float* db1 = (const float*)d_in[14];
    float* out = (float*)d_out;

    gru_fused_kernel<<<256, NTH, 0, stream>>>(
        x, ew0, eb0, ew1, eb1, ew2, eb2, wih, whh, bih, bhh,
        dw0, db0, dw1, db1, out);
}

// Round 4
// 160.508 us; speedup vs baseline: 1.2878x; 1.2878x over previous
//
#include <hip/hip_runtime.h>

#define NTH 256   // 4 waves; 16 rows/block; grid 512 -> 2 blocks/CU

typedef _Float16 half8 __attribute__((ext_vector_type(8)));
typedef _Float16 half4 __attribute__((ext_vector_type(4)));
typedef __attribute__((ext_vector_type(4))) float floatx4;

#define LOG2E 1.44269504088896340736f

// DPP add stage; 0x140,0x141,0x4E,0xB1 together = 16-lane sum broadcast
template<int CTRL>
__device__ __forceinline__ float dpp_add(float v) {
    int o = __builtin_amdgcn_update_dpp(0, __float_as_int(v), CTRL, 0xF, 0xF, true);
    return v + __int_as_float(o);
}

#define MFMA16 __builtin_amdgcn_mfma_f32_16x16x32_f16

// ---------------------------------------------------------------------------
// Encoder layer core (MFMA): acc[nt] = bias + src[16,K] @ W[K,128] on cols
// jc = w*32 + nt*16 + l15. src is f16 LDS, rows of ROWH halves, 8-elem chunks
// rotation-swizzled by row with mask CMASK. W gathered from global (L2-hot).
// ---------------------------------------------------------------------------
template<int KTILES, int CMASK, int ROWH>
__device__ __forceinline__ void enc_layer(const _Float16* __restrict__ src,
                                          const float* __restrict__ W,
                                          const float* __restrict__ bias,
                                          int w, int quad, int l15,
                                          floatx4 acc[2]) {
    half8 bw[2][KTILES];
    #pragma unroll
    for (int nt = 0; nt < 2; nt++) {
        const int jc = w * 32 + nt * 16 + l15;
        #pragma unroll
        for (int kt = 0; kt < KTILES; kt++) {
            const int kb = kt * 32 + quad * 8;
            half8 hv;
            #pragma unroll
            for (int e = 0; e < 8; e++) hv[e] = (_Float16)W[(kb + e) * 128 + jc];
            bw[nt][kt] = hv;
        }
        const float bv = bias[jc];
        acc[nt] = (floatx4){bv, bv, bv, bv};
    }
    #pragma unroll
    for (int kt = 0; kt < KTILES; kt++) {
        const half8 av = *(const half8*)(src + l15 * ROWH +
                                         (((kt * 4 + quad) + l15) & CMASK) * 8);
        acc[0] = MFMA16(av, bw[0][kt], acc[0], 0, 0, 0);
        acc[1] = MFMA16(av, bw[1][kt], acc[1], 0, 0, 0);
    }
}

// store MFMA C (row=quad*4+reg, col=jc) into f16 [16][128] with &15 swizzle
__device__ __forceinline__ void enc_store(_Float16* __restrict__ dst,
                                          const floatx4 acc[2],
                                          int w, int quad, int l15, bool relu) {
    #pragma unroll
    for (int nt = 0; nt < 2; nt++) {
        const int jc = w * 32 + nt * 16 + l15;
        #pragma unroll
        for (int reg = 0; reg < 4; reg++) {
            const int row = quad * 4 + reg;
            float v = acc[nt][reg];
            if (relu) v = fmaxf(v, 0.f);
            dst[row * 128 + ((((jc >> 3) + row) & 15) << 3) + (jc & 7)] = (_Float16)v;
        }
    }
}

// ---------------------------------------------------------------------------
// Fully-MFMA encoder + 50-iter GRU + decoder. 16 rows/block, 4 waves; wave w
// owns gate cols {g*128 + w*32 + nt*16 + l15}. 2 blocks/CU, 256-VGPR budget
// (launch_bounds(256,2)) so W_hh (96 VGPR) + decoder W (16) persist with no
// spills. Per-CU LDS read volume minimized (32 b128/iter). All h-plane LDS
// traffic chunk-rotation swizzled. Gate nonlinearity: exp2-domain prescale +
// merged z/n reciprocal: h' = [Ez(Ey-1) + h(Ey+1)] / [(Ey+1)(Ez+1)].
// ---------------------------------------------------------------------------
__global__ __launch_bounds__(NTH, 2)
void gru_fused_kernel(const float* __restrict__ x,
                      const float* __restrict__ ew0, const float* __restrict__ eb0,
                      const float* __restrict__ ew1, const float* __restrict__ eb1,
                      const float* __restrict__ ew2, const float* __restrict__ eb2,
                      const float* __restrict__ w_ih, const float* __restrict__ w_hh,
                      const float* __restrict__ b_ih, const float* __restrict__ b_hh,
                      const float* __restrict__ dw0, const float* __restrict__ db0,
                      const float* __restrict__ dw1, const float* __restrict__ db1,
                      float* __restrict__ out) {
    __shared__ __align__(16) _Float16 encx[16 * 256];   // x stage (8KB); reused as h2
    __shared__ __align__(16) _Float16 h1b[16 * 128];    // layer-1 out (4KB)
    __shared__ __align__(16) _Float16 h16[2 * 16 * 128];// h planes dbuf (8KB)
    __shared__ float outb[16][52];

    const int tid  = threadIdx.x;
    const int b0   = blockIdx.x * 16;
    const int lane = tid & 63;
    const int w    = tid >> 6;     // wave 0..3
    const int quad = lane >> 4;
    const int l15  = lane & 15;

    // ---------------- stage x -> f16 LDS (chunk-rotation swizzle &31) ------
    #pragma unroll
    for (int i = 0; i < 4; i++) {
        const int e = tid + i * NTH;          // 0..1023 float4s
        const int row = e >> 6, c4 = e & 63;
        const float4 xv = *(const float4*)(x + (size_t)(b0 + row) * 256 + c4 * 4);
        half4 hv = {(_Float16)xv.x, (_Float16)xv.y, (_Float16)xv.z, (_Float16)xv.w};
        *(half4*)(encx + row * 256 + (((c4 >> 1) + row) & 31) * 8 + (c4 & 1) * 4) = hv;
    }
    __syncthreads();

    // ---------------- encoder: 3 MFMA layers ----------------
    floatx4 ea[2];
    enc_layer<8, 31, 256>(encx, ew0, eb0, w, quad, l15, ea);
    enc_store(h1b, ea, w, quad, l15, true);
    __syncthreads();
    enc_layer<4, 15, 128>(h1b, ew1, eb1, w, quad, l15, ea);
    enc_store(encx, ea, w, quad, l15, true);       // h2 reuses encx (stride 128)
    __syncthreads();
    enc_layer<4, 15, 128>(encx, ew2, eb2, w, quad, l15, ea);
    // h_0: keep fp32 lane-private copy; publish f16 plane 0
    float hold[2][4];
    #pragma unroll
    for (int nt = 0; nt < 2; nt++)
        #pragma unroll
        for (int reg = 0; reg < 4; reg++) hold[nt][reg] = ea[nt][reg];
    enc_store(h16, ea, w, quad, l15, false);
    if (tid < 16) outb[tid][0] = 0.f;

    // ---------------- persistent register weights (f16, exp2-prescaled) ----
    half8 wb16[3][2][4];
    #pragma unroll
    for (int g = 0; g < 3; g++) {
        const float scale = (g == 2) ? 2.f * LOG2E : LOG2E;
        #pragma unroll
        for (int nt = 0; nt < 2; nt++) {
            const float* wrow = w_hh + (g * 128 + w * 32 + nt * 16 + l15) * 128;
            #pragma unroll
            for (int kt = 0; kt < 4; kt++) {
                const int kb = kt * 32 + quad * 8;
                half8 hv;
                #pragma unroll
                for (int e = 0; e < 8; e++) hv[e] = (_Float16)(wrow[kb + e] * scale);
                wb16[g][nt][kt] = hv;
            }
        }
    }
    half8 dw16[4];
    #pragma unroll
    for (int kt = 0; kt < 4; kt++) {
        half8 hv;
        #pragma unroll
        for (int e = 0; e < 8; e++)
            hv[e] = (_Float16)dw0[(kt * 32 + quad * 8 + e) * 16 + l15];
        dw16[kt] = hv;
    }
    // gate constants per nt (exp2-prescaled; biases fold into acc init)
    float wr[2], wz[2], wn[2], c_r[2], c_z[2], c_n[2], bnih[2];
    int jcw[2];
    #pragma unroll
    for (int nt = 0; nt < 2; nt++) {
        const int jc = w * 32 + nt * 16 + l15;
        jcw[nt]  = jc;
        wr[nt]   = w_ih[jc] * LOG2E;
        wz[nt]   = w_ih[128 + jc] * LOG2E;
        wn[nt]   = w_ih[256 + jc] * (2.f * LOG2E);
        c_r[nt]  = (b_ih[jc] + b_hh[jc]) * LOG2E;
        c_z[nt]  = (b_ih[128 + jc] + b_hh[128 + jc]) * LOG2E;
        c_n[nt]  = b_hh[256 + jc] * (2.f * LOG2E);
        bnih[nt] = b_ih[256 + jc] * (2.f * LOG2E);
    }
    const float db0r = db0[l15];
    const float dw1r = dw1[l15];
    const float db1r = db1[0];
    __syncthreads();

    // ---------------- 50 iterations: dec(h_t) -> out[t]; gates -> h_{t+1} ---
    for (int t = 0; t <= 49; t++) {
        const int cur = t & 1, nxt = cur ^ 1;
        const _Float16* __restrict__ hc = h16 + cur * 2048;
        _Float16* __restrict__ hw = h16 + nxt * 2048;

        // A-frags (4x ds_read_b128, swizzled)
        half8 ah[4];
        #pragma unroll
        for (int kt = 0; kt < 4; kt++)
            ah[kt] = *(const half8*)(hc + l15 * 128 +
                                     (((kt * 4 + quad) + l15) & 15) * 8);

        // decoder first (dacc feeds the serial reduce->gate chain)
        floatx4 dacc = (floatx4){0.f, 0.f, 0.f, 0.f};
        #pragma unroll
        for (int kt = 0; kt < 4; kt++)
            dacc = MFMA16(ah[kt], dw16[kt], dacc, 0, 0, 0);

        // GRU MFMAs: biases pre-loaded into accumulators
        floatx4 acc[3][2];
        #pragma unroll
        for (int nt = 0; nt < 2; nt++) {
            acc[0][nt] = (floatx4){c_r[nt], c_r[nt], c_r[nt], c_r[nt]};
            acc[1][nt] = (floatx4){c_z[nt], c_z[nt], c_z[nt], c_z[nt]};
            acc[2][nt] = (floatx4){c_n[nt], c_n[nt], c_n[nt], c_n[nt]};
        }
        #pragma unroll
        for (int kt = 0; kt < 4; kt++)
            #pragma unroll
            for (int g = 0; g < 3; g++) {
                acc[g][0] = MFMA16(ah[kt], wb16[g][0][kt], acc[g][0], 0, 0, 0);
                acc[g][1] = MFMA16(ah[kt], wb16[g][1][kt], acc[g][1], 0, 0, 0);
            }

        // decoder reduce via DPP (16-lane sum within quad-row, broadcast)
        float xp[4];
        #pragma unroll
        for (int reg = 0; reg < 4; reg++) {
            float v = fmaxf(dacc[reg] + db0r, 0.f) * dw1r;
            v = dpp_add<0x140>(v);   // row_mirror
            v = dpp_add<0x141>(v);   // row_half_mirror
            v = dpp_add<0x4E>(v);    // quad_perm xor2
            v = dpp_add<0xB1>(v);    // quad_perm xor1
            xp[reg] = (t == 0) ? 0.f : (v + db1r);
        }
        if (t > 0 && w == 0 && l15 == 0) {
            #pragma unroll
            for (int reg = 0; reg < 4; reg++)
                outb[quad * 4 + reg][t] = xp[reg];
        }

        // gates -> h_{t+1}; merged z/n single-rcp update
        if (t < 49) {
            #pragma unroll
            for (int nt = 0; nt < 2; nt++)
                #pragma unroll
                for (int reg = 0; reg < 4; reg++) {
                    const int row = quad * 4 + reg;
                    const float xpv = xp[reg];
                    const float hv0 = hold[nt][reg];
                    float gr = fmaf(xpv, wr[nt], acc[0][nt][reg]);
                    float gz = fmaf(xpv, wz[nt], acc[1][nt][reg]);
                    float Er = __builtin_amdgcn_exp2f(-gr);
                    float rg = __builtin_amdgcn_rcpf(1.f + Er);
                    float ys = fmaf(rg, acc[2][nt][reg], fmaf(xpv, wn[nt], bnih[nt]));
                    float Ey = __builtin_amdgcn_exp2f(ys);
                    float Ez = __builtin_amdgcn_exp2f(-gz);
                    // h' = [Ez(Ey-1) + h(Ey+1)] / [(Ey+1)(Ez+1)]
                    float num = fmaf(Ez, Ey, -Ez) + fmaf(hv0, Ey, hv0);
                    float den = fmaf(Ey, Ez, Ey) + (Ez + 1.f);
                    const float hn = num * __builtin_amdgcn_rcpf(den);
                    hold[nt][reg] = hn;
                    hw[row * 128 + ((((jcw[nt] >> 3) + row) & 15) << 3) +
                       (jcw[nt] & 7)] = (_Float16)hn;
                }
        }
        __syncthreads();   // plane[nxt] complete; outb[t] visible
    }

    // coalesced output write: [16 rows][50 cols], col 0 = 0
    for (int e = tid; e < 16 * 50; e += NTH) {
        const int b = e / 50;
        const int tcol = e - b * 50;
        out[(size_t)b0 * 50 + e] = outb[b][tcol];
    }
}

// ---------------------------------------------------------------------------
extern "C" void kernel_launch(void* const* d_in, const int* in_sizes, int n_in,
                              void* d_out, int out_size, void* d_ws, size_t ws_size,
                              hipStream_t stream) {
    const float* x   = (const float*)d_in[0];
    const float* ew0 = (const float*)d_in[1];
    const float* eb0 = (const float*)d_in[2];
    const float* ew1 = (const float*)d_in[3];
    const float* eb1 = (const float*)d_in[4];
    const float* ew2 = (const float*)d_in[5];
    const float* eb2 = (const float*)d_in[6];
    const float* wih = (const float*)d_in[7];
    const float* whh = (const float*)d_in[8];
    const float* bih = (const float*)d_in[9];
    const float* bhh = (const float*)d_in[10];
    const float* dw0 = (const float*)d_in[11];
    const float* db0 = (const float*)d_in[12];
    const float* dw1 = (const float*)d_in[13];
    const float* db1 = (const float*)d_in[14];
    float* out = (float*)d_out;

    gru_fused_kernel<<<512, NTH, 0, stream>>>(
        x, ew0, eb0, ew1, eb1, ew2, eb2, wih, whh, bih, bhh,
        dw0, db0, dw1, db1, out);
}